// Round 1
// baseline (903.232 us; speedup 1.0000x reference)
//
#include <hip/hip_runtime.h>
#include <math.h>
#include <stdint.h>
#include <stddef.h>

// ---------------------------------------------------------------------------
// Attention layer for MI355X (gfx950). I/O fp32; internal bf16 MFMA pipeline.
//   cvt: x/wq/wk/wv/wo -> bf16
//   qkv_proj (gemm_bt): Q(2048,4096), K(2048,1024), V -> V^T(1024,2048)
//   RoPE(Q), RoPE(K)
//   flash_attn: LDS-free, key-permuted S^T trick, causal, GQA rep=4
//               + register double-buffered K/V prefetch (hide global latency)
//               + defer-max rescale (skip O-rescale when max growth <= 8)
//   oproj (gemm_bt): out fp32
// Only mfma_f32_16x16x32_bf16 is used (HW-verified layouts m89/m97).
// ---------------------------------------------------------------------------

typedef __attribute__((ext_vector_type(8))) short bf16x8;
typedef __attribute__((ext_vector_type(4))) short bf16x4;
typedef __attribute__((ext_vector_type(4))) float f32x4;
typedef unsigned short u16;

#define NEG_BIG (-1.0e9f)
#define MFMA32(a, b, c) __builtin_amdgcn_mfma_f32_16x16x32_bf16(a, b, c, 0, 0, 0)

__device__ __forceinline__ float bf2f(u16 b) {
    return __uint_as_float(((unsigned int)b) << 16);
}
__device__ __forceinline__ u16 f2bf(float f) {
    unsigned int u = __float_as_uint(f);
    u += 0x7fff + ((u >> 16) & 1);   // RNE
    return (u16)(u >> 16);
}
__device__ __forceinline__ void gld_lds16(short* lds, const u16* g) {
    __builtin_amdgcn_global_load_lds(
        (const __attribute__((address_space(1))) void*)g,
        (__attribute__((address_space(3))) void*)lds, 16, 0, 0);
}

// ---------------------------------------------------------------------------
// fp32 -> bf16 bulk convert (n multiple of 8)
// ---------------------------------------------------------------------------
__global__ __launch_bounds__(256) void cvt_bf16(const float* __restrict__ src,
                                                u16* __restrict__ dst, int n) {
    int i = (blockIdx.x * blockDim.x + threadIdx.x) * 8;
    if (i >= n) return;
    float4 a, b;
    __builtin_memcpy(&a, src + i, 16);
    __builtin_memcpy(&b, src + i + 4, 16);
    bf16x8 o;
    o[0] = (short)f2bf(a.x); o[1] = (short)f2bf(a.y);
    o[2] = (short)f2bf(a.z); o[3] = (short)f2bf(a.w);
    o[4] = (short)f2bf(b.x); o[5] = (short)f2bf(b.y);
    o[6] = (short)f2bf(b.z); o[7] = (short)f2bf(b.w);
    __builtin_memcpy(dst + i, &o, 16);
}

// ---------------------------------------------------------------------------
// m97-style gemm_bt: C = A[M,K] @ B[N,K]^T, bf16 in, fp32 accum.
// OUT: 0 = bf16 row-major, 1 = fp32 row-major, 2 = bf16 transposed [N][2048]
// ---------------------------------------------------------------------------
template <int OUT>
__device__ __forceinline__ void gemm_tile_bt(const u16* __restrict__ A,
                                             const u16* __restrict__ B,
                                             void* __restrict__ C,
                                             int mb, int nb, int N, int K,
                                             short* As, short* Bs) {
    const int t = threadIdx.x;
    const int lane = t & 63, wave = t >> 6;
    const int l15 = lane & 15, quad = lane >> 4;
    const int wm = (wave >> 1) * 64, wn = (wave & 1) * 64;
    f32x4 acc[4][4] = {};

    const int r0 = t >> 2, cc0 = (t & 3) * 8;
    const u16* Ap0 = A + (size_t)(mb * 128 + r0) * K + cc0;
    const u16* Ap1 = Ap0 + (size_t)64 * K;
    const u16* Bp0 = B + (size_t)(nb * 128 + r0) * K + cc0;
    const u16* Bp1 = Bp0 + (size_t)64 * K;
    short* asd0 = As + t * 8; short* asd1 = As + (t + 256) * 8;
    short* bsd0 = Bs + t * 8; short* bsd1 = Bs + (t + 256) * 8;

    int aoff[4], boff[4];
#pragma unroll
    for (int i = 0; i < 4; ++i) {
        aoff[i] = (wm + i * 16 + l15) * 32 + quad * 8;
        boff[i] = (wn + i * 16 + l15) * 32 + quad * 8;
    }

    for (int kb = 0; kb < K; kb += 32) {
        gld_lds16(asd0, Ap0 + kb);
        gld_lds16(asd1, Ap1 + kb);
        gld_lds16(bsd0, Bp0 + kb);
        gld_lds16(bsd1, Bp1 + kb);
        __syncthreads();
        bf16x8 af[4], bfr[4];
#pragma unroll
        for (int i = 0; i < 4; ++i) __builtin_memcpy(&af[i], As + aoff[i], 16);
#pragma unroll
        for (int j = 0; j < 4; ++j) __builtin_memcpy(&bfr[j], Bs + boff[j], 16);
#pragma unroll
        for (int i = 0; i < 4; ++i)
#pragma unroll
            for (int j = 0; j < 4; ++j)
                acc[i][j] = MFMA32(af[i], bfr[j], acc[i][j]);
        __syncthreads();
    }

    // C/D layout: col = lane&15, row = quad*4 + reg
#pragma unroll
    for (int i = 0; i < 4; ++i)
#pragma unroll
        for (int j = 0; j < 4; ++j) {
            if (OUT == 2) {
                // transposed write: [col][seq], 4 consecutive rows -> 8B store
                int col = nb * 128 + wn + j * 16 + l15;
                int row0 = mb * 128 + wm + i * 16 + quad * 4;
                bf16x4 v;
#pragma unroll
                for (int r = 0; r < 4; ++r) v[r] = (short)f2bf(acc[i][j][r]);
                __builtin_memcpy((u16*)C + (size_t)col * 2048 + row0, &v, 8);
            } else {
#pragma unroll
                for (int r = 0; r < 4; ++r) {
                    int row = mb * 128 + wm + i * 16 + quad * 4 + r;
                    int col = nb * 128 + wn + j * 16 + l15;
                    if (OUT == 1)
                        ((float*)C)[(size_t)row * N + col] = acc[i][j][r];
                    else
                        ((u16*)C)[(size_t)row * N + col] = f2bf(acc[i][j][r]);
                }
            }
        }
}

__global__ __launch_bounds__(256) void qkv_proj(
    const u16* __restrict__ x,
    const u16* __restrict__ wq, const u16* __restrict__ wk,
    const u16* __restrict__ wv,
    u16* __restrict__ Q, u16* __restrict__ Kc, u16* __restrict__ Vt) {
    __shared__ __align__(16) short As[128 * 32];
    __shared__ __align__(16) short Bs[128 * 32];
    int mb = blockIdx.x, y = blockIdx.y;
    if (y < 32)
        gemm_tile_bt<0>(x, wq, Q, mb, y, 4096, 4096, As, Bs);
    else if (y < 40)
        gemm_tile_bt<0>(x, wk, Kc, mb, y - 32, 1024, 4096, As, Bs);
    else
        gemm_tile_bt<2>(x, wv, Vt, mb, y - 40, 1024, 4096, As, Bs);
}

__global__ __launch_bounds__(256) void oproj(
    const u16* __restrict__ A, const u16* __restrict__ wo,
    float* __restrict__ out) {
    __shared__ __align__(16) short As[128 * 32];
    __shared__ __align__(16) short Bs[128 * 32];
    gemm_tile_bt<1>(A, wo, out, blockIdx.x, blockIdx.y, 4096, 4096, As, Bs);
}

// ---------------------------------------------------------------------------
// RoPE in-place: X viewed as (2048, nheads, 64 pairs of 2); cos/sin fp32
// ---------------------------------------------------------------------------
__global__ void rope_kernel(u16* __restrict__ X,
                            const float* __restrict__ cosb,
                            const float* __restrict__ sinb, int nheads) {
    int idx = blockIdx.x * blockDim.x + threadIdx.x;
    int total = 2048 * nheads * 64;
    if (idx >= total) return;
    int i = idx % 64;
    int h = (idx / 64) % nheads;
    int s = idx / (64 * nheads);
    u16* p = X + (size_t)s * nheads * 128 + h * 128 + 2 * i;
    float x0 = bf2f(p[0]), x1 = bf2f(p[1]);
    float c = cosb[s * 64 + i], sn = sinb[s * 64 + i];
    p[0] = f2bf(x0 * c - x1 * sn);
    p[1] = f2bf(x0 * sn + x1 * c);
}

// ---------------------------------------------------------------------------
// LDS-free flash attention with key-permuted S^T.
// S^T = K.Q^T via mfma_16x16x32, with K rows permuted so the C-layout lane
// (quad,c) holds keys kb+8*quad+{0..3} (s0) and +4..7 (s1). That IS the
// 16x16x32 A-operand layout (k=quad*8+j) -> P feeds PV with zero movement.
// V pre-transposed globally: Vt[feature][seq]; PV B-frag = 16B contiguous.
//
// This version: register double-buffered K/V. The 16 global loads for
// iteration i+1 are issued textually right after iteration i's S-MFMAs, so
// their latency is covered by softmax + PV + the sibling wave. Rescale of O
// (4 serial shfl broadcast + 32 mults) is skipped when the running max grew
// by <= 8 (defer-max, THR=8; p <= e^8 is safe in f32/bf16).
// ---------------------------------------------------------------------------
__device__ __forceinline__ void fa_load(int kb, const u16* __restrict__ kb0,
                                        const u16* __restrict__ vb0,
                                        bf16x8 (&kf)[8], bf16x8 (&vf)[8]) {
    const u16* ka = kb0 + (size_t)kb * 1024;
#pragma unroll
    for (int c = 0; c < 4; ++c) {
        __builtin_memcpy(&kf[c], ka + c * 32, 16);
        __builtin_memcpy(&kf[4 + c], ka + 4 * 1024 + c * 32, 16);
    }
    const u16* va = vb0 + kb;
#pragma unroll
    for (int n = 0; n < 8; ++n)
        __builtin_memcpy(&vf[n], va + (size_t)n * 16 * 2048, 16);
}

template <bool PRE, bool MASKED>
__device__ __forceinline__ void fa_step(
    int kb, int q0, int l15, int quad,
    const u16* __restrict__ kb0, const u16* __restrict__ vb0,
    const bf16x8 (&qf)[4],
    const bf16x8 (&kc)[8], const bf16x8 (&vc)[8],   // current frags
    bf16x8 (&kn)[8], bf16x8 (&vn)[8],               // next frags (filled if PRE)
    f32x4 (&o)[8], float& m, float& l) {
    const float scale = 0.08838834764831845f;  // 1/sqrt(128)

    // S^T = K.Q^T : two 16-key subtiles (keys already permuted into A-layout)
    f32x4 s0 = {0, 0, 0, 0}, s1 = {0, 0, 0, 0};
#pragma unroll
    for (int c = 0; c < 4; ++c) {
        s0 = MFMA32(kc[c], qf[c], s0);
        s1 = MFMA32(kc[4 + c], qf[c], s1);
    }

    // Prefetch next iteration's K/V frags NOW: latency hides under softmax+PV.
    if (PRE) {
        const u16* ka = kb0 + (size_t)(kb + 32) * 1024;
#pragma unroll
        for (int c = 0; c < 4; ++c) {
            __builtin_memcpy(&kn[c], ka + c * 32, 16);
            __builtin_memcpy(&kn[4 + c], ka + 4 * 1024 + c * 32, 16);
        }
        const u16* va = vb0 + kb + 32;
#pragma unroll
        for (int n = 0; n < 8; ++n)
            __builtin_memcpy(&vn[n], va + (size_t)n * 16 * 2048, 16);
    }

    // scale + causal mask. Lane (quad,l15): s0[r] = key kb+8*quad+r,
    // s1[r] = key kb+8*quad+4+r, q column = l15.
    float sv0[4], sv1[4];
    const int q = q0 + l15;
#pragma unroll
    for (int r = 0; r < 4; ++r) {
        sv0[r] = s0[r] * scale;
        sv1[r] = s1[r] * scale;
        if (MASKED) {
            if (kb + 8 * quad + r > q) sv0[r] = NEG_BIG;
            if (kb + 8 * quad + 4 + r > q) sv1[r] = NEG_BIG;
        }
    }

    // online softmax: all 32 keys of q-col l15 spread across quads
    float mx = fmaxf(fmaxf(fmaxf(sv0[0], sv0[1]), fmaxf(sv0[2], sv0[3])),
                     fmaxf(fmaxf(sv1[0], sv1[1]), fmaxf(sv1[2], sv1[3])));
    mx = fmaxf(mx, __shfl_xor(mx, 16));
    mx = fmaxf(mx, __shfl_xor(mx, 32));

    // defer-max: only rescale O when the max actually grew past the threshold
    float alpha = 1.0f;
    if (!__all(mx <= m + 8.0f)) {
        float mnew = fmaxf(m, mx);
        alpha = __expf(m - mnew);
        // broadcast alpha from q=l15 lanes to O's q=quad*4+r rows
        float aO[4];
#pragma unroll
        for (int r = 0; r < 4; ++r) aO[r] = __shfl(alpha, quad * 20 + r);
#pragma unroll
        for (int n = 0; n < 8; ++n)
#pragma unroll
            for (int r = 0; r < 4; ++r) o[n][r] *= aO[r];
        m = mnew;
    }

    float p0[4], p1[4], sum = 0.f;
#pragma unroll
    for (int r = 0; r < 4; ++r) {
        p0[r] = __expf(sv0[r] - m);
        p1[r] = __expf(sv1[r] - m);
        sum += p0[r] + p1[r];
    }
    sum += __shfl_xor(sum, 16);
    sum += __shfl_xor(sum, 32);
    l = l * alpha + sum;

    // pack P into the 16x16x32 A-frag: element j = key 8*quad+j  (zero move)
    bf16x8 pa;
#pragma unroll
    for (int r = 0; r < 4; ++r) {
        pa[r] = (short)f2bf(p0[r]);
        pa[4 + r] = (short)f2bf(p1[r]);
    }

    // O += P.V : B-frag already in registers (vc)
#pragma unroll
    for (int n = 0; n < 8; ++n) o[n] = MFMA32(pa, vc[n], o[n]);
}

__device__ __forceinline__ void fa_task(
    const u16* __restrict__ Q, const u16* __restrict__ Kp,
    const u16* __restrict__ Vt, u16* __restrict__ O,
    int q0, int h, int kvh, int l15, int quad) {
    // Q B-frags (n=q=l15, k=d chunks)
    bf16x8 qf[4];
    const u16* qp = Q + (size_t)(q0 + l15) * 4096 + h * 128 + quad * 8;
#pragma unroll
    for (int c = 0; c < 4; ++c) __builtin_memcpy(&qf[c], qp + c * 32, 16);

    f32x4 o[8] = {};
    float m = NEG_BIG, l = 0.f;

    // key-permuted K base: A-row l15 of s0 loads key row 8*(l15>>2)+(l15&3)
    const int krow = 8 * (l15 >> 2) + (l15 & 3);
    const u16* kb0 = Kp + (size_t)krow * 1024 + kvh * 128 + quad * 8;
    const u16* vb0 = Vt + (size_t)(kvh * 128 + l15) * 2048 + quad * 8;

    const int n32 = (q0 + 47) / 32;  // 32-key blocks; only the last is masked

    // register double-buffer: iteration i lives in A if i even, B if i odd
    bf16x8 kA[8], vA[8], kB[8], vB[8];
    fa_load(0, kb0, vb0, kA, vA);
    int i = 0;
    while (i < n32 - 1) {
        fa_step<true, false>(32 * i, q0, l15, quad, kb0, vb0, qf,
                             kA, vA, kB, vB, o, m, l);
        ++i;
        if (i >= n32 - 1) break;
        fa_step<true, false>(32 * i, q0, l15, quad, kb0, vb0, qf,
                             kB, vB, kA, vA, o, m, l);
        ++i;
    }
    if (i & 1)
        fa_step<false, true>(32 * i, q0, l15, quad, kb0, vb0, qf,
                             kB, vB, kA, vA, o, m, l);
    else
        fa_step<false, true>(32 * i, q0, l15, quad, kb0, vb0, qf,
                             kA, vA, kB, vB, o, m, l);

    // epilogue: O rows are q=quad*4+r; fetch l from q=l15 lanes
    float inv[4];
#pragma unroll
    for (int r = 0; r < 4; ++r) inv[r] = 1.f / __shfl(l, quad * 20 + r);
#pragma unroll
    for (int n = 0; n < 8; ++n)
#pragma unroll
        for (int r = 0; r < 4; ++r) {
            int row = q0 + quad * 4 + r;
            O[(size_t)row * 4096 + h * 128 + n * 16 + l15] =
                f2bf(o[n][r] * inv[r]);
        }
}

__global__ __launch_bounds__(256, 2) void flash_attn(
    const u16* __restrict__ Q, const u16* __restrict__ Kp,
    const u16* __restrict__ Vt, u16* __restrict__ O) {
    const int pp = blockIdx.x;   // 0..15  (q-tile pair: pp and 31-pp)
    const int h = blockIdx.y;    // 0..31
    const int kvh = h >> 2;
    const int lane = threadIdx.x & 63, wave = threadIdx.x >> 6;
    const int l15 = lane & 15, quad = lane >> 4;
    // wave w of tile pp pairs with wave 3-w of tile 31-pp: 65 iters/wave, flat
    fa_task(Q, Kp, Vt, O, pp * 64 + wave * 16, h, kvh, l15, quad);
    fa_task(Q, Kp, Vt, O, (31 - pp) * 64 + (3 - wave) * 16, h, kvh, l15, quad);
}

// ---------------------------------------------------------------------------
extern "C" void kernel_launch(void* const* d_in, const int* in_sizes, int n_in,
                              void* d_out, int out_size, void* d_ws,
                              size_t ws_size, hipStream_t stream) {
    const float* x  = (const float*)d_in[0];
    const float* wq = (const float*)d_in[1];
    const float* wk = (const float*)d_in[2];
    const float* wv = (const float*)d_in[3];
    const float* wo = (const float*)d_in[4];
    const float* fc = (const float*)d_in[5];
    const float* fs = (const float*)d_in[6];
    float* out = (float*)d_out;

    const int NX = 2048 * 4096;
    const int NQW = 4096 * 4096;
    const int NKW = 1024 * 4096;
    const int NKV = 2048 * 1024;

    u16* Q   = (u16*)d_ws;
    u16* Kc  = Q   + NX;
    u16* Vt  = Kc  + NKV;   // [1024 features][2048 seq]
    u16* Ao  = Vt  + NKV;
    u16* xb  = Ao  + NX;
    u16* wqb = xb  + NX;
    u16* wkb = wqb + NQW;
    u16* wvb = wkb + NKW;
    u16* wob = wvb + NKW;

    cvt_bf16<<<NX / (256 * 8), 256, 0, stream>>>(x, xb, NX);
    cvt_bf16<<<NQW / (256 * 8), 256, 0, stream>>>(wq, wqb, NQW);
    cvt_bf16<<<NKW / (256 * 8), 256, 0, stream>>>(wk, wkb, NKW);
    cvt_bf16<<<NKW / (256 * 8), 256, 0, stream>>>(wv, wvb, NKW);
    cvt_bf16<<<NQW / (256 * 8), 256, 0, stream>>>(wo, wob, NQW);

    qkv_proj<<<dim3(16, 48), 256, 0, stream>>>(xb, wqb, wkb, wvb, Q, Kc, Vt);
    rope_kernel<<<(2048 * 32 * 64 + 255) / 256, 256, 0, stream>>>(Q, fc, fs, 32);
    rope_kernel<<<(2048 * 8 * 64 + 255) / 256, 256, 0, stream>>>(Kc, fc, fs, 8);
    flash_attn<<<dim3(16, 32), 256, 0, stream>>>(Q, Kc, Vt, Ao);
    oproj<<<dim3(16, 32), 256, 0, stream>>>(Ao, wob, out);
}

// Round 2
// 533.914 us; speedup vs baseline: 1.6917x; 1.6917x over previous
//
#include <hip/hip_runtime.h>
#include <math.h>
#include <stdint.h>
#include <stddef.h>

// ---------------------------------------------------------------------------
// Attention layer for MI355X (gfx950). I/O fp32; internal bf16 MFMA pipeline.
//   cvt: x/wq/wk/wv/wo -> bf16
//   qkv_proj (gemm_bt): Q(2048,4096), K(2048,1024), V -> V^T(1024,2048)
//   RoPE(Q), RoPE(K)
//   flash_attn: LDS-staged (async global_load_lds, double-buffered),
//               key-permuted S^T trick, causal, GQA rep=4, defer-max rescale
//   oproj (gemm_bt): out fp32
// Only mfma_f32_16x16x32_bf16 is used (HW-verified layouts m89/m97).
// ---------------------------------------------------------------------------

typedef __attribute__((ext_vector_type(8))) short bf16x8;
typedef __attribute__((ext_vector_type(4))) short bf16x4;
typedef __attribute__((ext_vector_type(4))) float f32x4;
typedef unsigned short u16;

#define NEG_BIG (-1.0e9f)
#define MFMA32(a, b, c) __builtin_amdgcn_mfma_f32_16x16x32_bf16(a, b, c, 0, 0, 0)

__device__ __forceinline__ float bf2f(u16 b) {
    return __uint_as_float(((unsigned int)b) << 16);
}
__device__ __forceinline__ u16 f2bf(float f) {
    unsigned int u = __float_as_uint(f);
    u += 0x7fff + ((u >> 16) & 1);   // RNE
    return (u16)(u >> 16);
}
__device__ __forceinline__ void gld_lds16(short* lds, const u16* g) {
    __builtin_amdgcn_global_load_lds(
        (const __attribute__((address_space(1))) void*)g,
        (__attribute__((address_space(3))) void*)lds, 16, 0, 0);
}

// ---------------------------------------------------------------------------
// fp32 -> bf16 bulk convert (n multiple of 8)
// ---------------------------------------------------------------------------
__global__ __launch_bounds__(256) void cvt_bf16(const float* __restrict__ src,
                                                u16* __restrict__ dst, int n) {
    int i = (blockIdx.x * blockDim.x + threadIdx.x) * 8;
    if (i >= n) return;
    float4 a, b;
    __builtin_memcpy(&a, src + i, 16);
    __builtin_memcpy(&b, src + i + 4, 16);
    bf16x8 o;
    o[0] = (short)f2bf(a.x); o[1] = (short)f2bf(a.y);
    o[2] = (short)f2bf(a.z); o[3] = (short)f2bf(a.w);
    o[4] = (short)f2bf(b.x); o[5] = (short)f2bf(b.y);
    o[6] = (short)f2bf(b.z); o[7] = (short)f2bf(b.w);
    __builtin_memcpy(dst + i, &o, 16);
}

// ---------------------------------------------------------------------------
// m97-style gemm_bt: C = A[M,K] @ B[N,K]^T, bf16 in, fp32 accum.
// OUT: 0 = bf16 row-major, 1 = fp32 row-major, 2 = bf16 transposed [N][2048]
// ---------------------------------------------------------------------------
template <int OUT>
__device__ __forceinline__ void gemm_tile_bt(const u16* __restrict__ A,
                                             const u16* __restrict__ B,
                                             void* __restrict__ C,
                                             int mb, int nb, int N, int K,
                                             short* As, short* Bs) {
    const int t = threadIdx.x;
    const int lane = t & 63, wave = t >> 6;
    const int l15 = lane & 15, quad = lane >> 4;
    const int wm = (wave >> 1) * 64, wn = (wave & 1) * 64;
    f32x4 acc[4][4] = {};

    const int r0 = t >> 2, cc0 = (t & 3) * 8;
    const u16* Ap0 = A + (size_t)(mb * 128 + r0) * K + cc0;
    const u16* Ap1 = Ap0 + (size_t)64 * K;
    const u16* Bp0 = B + (size_t)(nb * 128 + r0) * K + cc0;
    const u16* Bp1 = Bp0 + (size_t)64 * K;
    short* asd0 = As + t * 8; short* asd1 = As + (t + 256) * 8;
    short* bsd0 = Bs + t * 8; short* bsd1 = Bs + (t + 256) * 8;

    int aoff[4], boff[4];
#pragma unroll
    for (int i = 0; i < 4; ++i) {
        aoff[i] = (wm + i * 16 + l15) * 32 + quad * 8;
        boff[i] = (wn + i * 16 + l15) * 32 + quad * 8;
    }

    for (int kb = 0; kb < K; kb += 32) {
        gld_lds16(asd0, Ap0 + kb);
        gld_lds16(asd1, Ap1 + kb);
        gld_lds16(bsd0, Bp0 + kb);
        gld_lds16(bsd1, Bp1 + kb);
        __syncthreads();
        bf16x8 af[4], bfr[4];
#pragma unroll
        for (int i = 0; i < 4; ++i) __builtin_memcpy(&af[i], As + aoff[i], 16);
#pragma unroll
        for (int j = 0; j < 4; ++j) __builtin_memcpy(&bfr[j], Bs + boff[j], 16);
#pragma unroll
        for (int i = 0; i < 4; ++i)
#pragma unroll
            for (int j = 0; j < 4; ++j)
                acc[i][j] = MFMA32(af[i], bfr[j], acc[i][j]);
        __syncthreads();
    }

    // C/D layout: col = lane&15, row = quad*4 + reg
#pragma unroll
    for (int i = 0; i < 4; ++i)
#pragma unroll
        for (int j = 0; j < 4; ++j) {
            if (OUT == 2) {
                // transposed write: [col][seq], 4 consecutive rows -> 8B store
                int col = nb * 128 + wn + j * 16 + l15;
                int row0 = mb * 128 + wm + i * 16 + quad * 4;
                bf16x4 v;
#pragma unroll
                for (int r = 0; r < 4; ++r) v[r] = (short)f2bf(acc[i][j][r]);
                __builtin_memcpy((u16*)C + (size_t)col * 2048 + row0, &v, 8);
            } else {
#pragma unroll
                for (int r = 0; r < 4; ++r) {
                    int row = mb * 128 + wm + i * 16 + quad * 4 + r;
                    int col = nb * 128 + wn + j * 16 + l15;
                    if (OUT == 1)
                        ((float*)C)[(size_t)row * N + col] = acc[i][j][r];
                    else
                        ((u16*)C)[(size_t)row * N + col] = f2bf(acc[i][j][r]);
                }
            }
        }
}

__global__ __launch_bounds__(256) void qkv_proj(
    const u16* __restrict__ x,
    const u16* __restrict__ wq, const u16* __restrict__ wk,
    const u16* __restrict__ wv,
    u16* __restrict__ Q, u16* __restrict__ Kc, u16* __restrict__ Vt) {
    __shared__ __align__(16) short As[128 * 32];
    __shared__ __align__(16) short Bs[128 * 32];
    int mb = blockIdx.x, y = blockIdx.y;
    if (y < 32)
        gemm_tile_bt<0>(x, wq, Q, mb, y, 4096, 4096, As, Bs);
    else if (y < 40)
        gemm_tile_bt<0>(x, wk, Kc, mb, y - 32, 1024, 4096, As, Bs);
    else
        gemm_tile_bt<2>(x, wv, Vt, mb, y - 40, 1024, 4096, As, Bs);
}

__global__ __launch_bounds__(256) void oproj(
    const u16* __restrict__ A, const u16* __restrict__ wo,
    float* __restrict__ out) {
    __shared__ __align__(16) short As[128 * 32];
    __shared__ __align__(16) short Bs[128 * 32];
    gemm_tile_bt<1>(A, wo, out, blockIdx.x, blockIdx.y, 4096, 4096, As, Bs);
}

// ---------------------------------------------------------------------------
// RoPE in-place: X viewed as (2048, nheads, 64 pairs of 2); cos/sin fp32
// ---------------------------------------------------------------------------
__global__ void rope_kernel(u16* __restrict__ X,
                            const float* __restrict__ cosb,
                            const float* __restrict__ sinb, int nheads) {
    int idx = blockIdx.x * blockDim.x + threadIdx.x;
    int total = 2048 * nheads * 64;
    if (idx >= total) return;
    int i = idx % 64;
    int h = (idx / 64) % nheads;
    int s = idx / (64 * nheads);
    u16* p = X + (size_t)s * nheads * 128 + h * 128 + 2 * i;
    float x0 = bf2f(p[0]), x1 = bf2f(p[1]);
    float c = cosb[s * 64 + i], sn = sinb[s * 64 + i];
    p[0] = f2bf(x0 * c - x1 * sn);
    p[1] = f2bf(x0 * sn + x1 * c);
}

// ---------------------------------------------------------------------------
// Flash attention, LDS-staged (T3 minimum 2-phase pipeline).
//
// Per block (head h, paired q-tiles pp / 31-pp): all 4 waves share one KV
// head. K and V tiles for a 32-key block are staged cooperatively into
// double-buffered LDS via async global_load_lds (no VGPR cost):
//   K tile: [32 keys][128 dims]  8KB, XOR-swizzled 16B slots
//   V tile: [128 feats][32 keys] 8KB, linear (m97-class read pattern)
// Schedule per iteration: STAGE(ib+1) -> compute(ib) -> __syncthreads.
// The compiler-inserted vmcnt(0) before s_barrier drains the DMA; its
// latency hides under the full compute phase.
//
// K swizzle: 16B-slot index ^= f(row), f(row) = (row&3)|((row&8)>>1).
// Chosen so the 16 permuted key-rows read by one ds_read_b128 spread over
// all 8 bank clusters (8 lanes each = conflict-free optimum). The inverse
// permutation is applied to the per-lane GLOBAL source address (LDS dest
// of global_load_lds must stay linear).
//
// S^T = K.Q^T with key-permuted rows: C-layout lane (quad,c) holds keys
// kb+8*quad+{0..3} (s0) / +4..7 (s1) == the 16x16x32 A-operand layout, so
// P feeds PV with zero data movement. Online softmax with defer-max THR=8.
// ---------------------------------------------------------------------------
__device__ __forceinline__ int kswz(int row, int cs) {
    int f = (row & 3) | ((row & 8) >> 1);
    return row * 128 + ((cs ^ f) << 3);
}

template <bool MASKED>
__device__ __forceinline__ void fa_step_lds(
    const short* __restrict__ Kl, const short* __restrict__ Vl,
    int kb, int q0, int l15, int quad,
    const int (&koff)[8], const int (&voff)[8],
    const bf16x8 (&qf)[4], f32x4 (&o)[8], float& m, float& l) {
    const float scale = 0.08838834764831845f;  // 1/sqrt(128)

    // K frags from LDS (swizzled) + S^T = K.Q^T
    bf16x8 kf[8];
#pragma unroll
    for (int i = 0; i < 8; ++i) __builtin_memcpy(&kf[i], Kl + koff[i], 16);
    f32x4 s0 = {0, 0, 0, 0}, s1 = {0, 0, 0, 0};
#pragma unroll
    for (int c = 0; c < 4; ++c) {
        s0 = MFMA32(kf[c], qf[c], s0);
        s1 = MFMA32(kf[4 + c], qf[c], s1);
    }

    // V frags early: ds_read latency hides under softmax
    bf16x8 vf[8];
#pragma unroll
    for (int n = 0; n < 8; ++n) __builtin_memcpy(&vf[n], Vl + voff[n], 16);

    // scale + causal mask. Lane (quad,l15): s0[r] = key kb+8*quad+r,
    // s1[r] = key kb+8*quad+4+r, q column = l15.
    float sv0[4], sv1[4];
    const int q = q0 + l15;
#pragma unroll
    for (int r = 0; r < 4; ++r) {
        sv0[r] = s0[r] * scale;
        sv1[r] = s1[r] * scale;
        if (MASKED) {
            if (kb + 8 * quad + r > q) sv0[r] = NEG_BIG;
            if (kb + 8 * quad + 4 + r > q) sv1[r] = NEG_BIG;
        }
    }

    // online softmax: all 32 keys of q-col l15 spread across quads
    float mx = fmaxf(fmaxf(fmaxf(sv0[0], sv0[1]), fmaxf(sv0[2], sv0[3])),
                     fmaxf(fmaxf(sv1[0], sv1[1]), fmaxf(sv1[2], sv1[3])));
    mx = fmaxf(mx, __shfl_xor(mx, 16));
    mx = fmaxf(mx, __shfl_xor(mx, 32));

    // defer-max: only rescale O when the max grew past the threshold
    float alpha = 1.0f;
    if (!__all(mx <= m + 8.0f)) {
        float mnew = fmaxf(m, mx);
        alpha = __expf(m - mnew);
        float aO[4];
#pragma unroll
        for (int r = 0; r < 4; ++r) aO[r] = __shfl(alpha, quad * 20 + r);
#pragma unroll
        for (int n = 0; n < 8; ++n)
#pragma unroll
            for (int r = 0; r < 4; ++r) o[n][r] *= aO[r];
        m = mnew;
    }

    float p0[4], p1[4], sum = 0.f;
#pragma unroll
    for (int r = 0; r < 4; ++r) {
        p0[r] = __expf(sv0[r] - m);
        p1[r] = __expf(sv1[r] - m);
        sum += p0[r] + p1[r];
    }
    sum += __shfl_xor(sum, 16);
    sum += __shfl_xor(sum, 32);
    l = l * alpha + sum;

    // pack P into the 16x16x32 A-frag: element j = key 8*quad+j (zero move)
    bf16x8 pa;
#pragma unroll
    for (int r = 0; r < 4; ++r) {
        pa[r] = (short)f2bf(p0[r]);
        pa[4 + r] = (short)f2bf(p1[r]);
    }

    // O += P.V
#pragma unroll
    for (int n = 0; n < 8; ++n) o[n] = MFMA32(pa, vf[n], o[n]);
}

__device__ __forceinline__ void fa_task(
    const u16* __restrict__ Q, const u16* __restrict__ Kc,
    const u16* __restrict__ Vt, u16* __restrict__ O,
    short* __restrict__ Kl0, short* __restrict__ Vl0,
    int q0, int nbt, int h, int kvh, int t) {
    const int lane = t & 63;
    const int l15 = lane & 15, quad = lane >> 4;

    // Q B-frags (n=q=l15, k=d chunks)
    bf16x8 qf[4];
    const u16* qp = Q + (size_t)(q0 + l15) * 4096 + h * 128 + quad * 8;
#pragma unroll
    for (int c = 0; c < 4; ++c) __builtin_memcpy(&qf[c], qp + c * 32, 16);

    // ---- staging addresses (per-thread constants) ----
    // K: rounds r=0,1; LDS linear chunk m = t+256r -> row m>>4, slot t&15.
    //    global source column-slot = slot ^ f(row)  (inverse of read swizzle)
    const u16* ksrc[2]; short* kdst[2];
    const u16* vsrc[2]; short* vdst[2];
#pragma unroll
    for (int r = 0; r < 2; ++r) {
        int row = (t >> 4) + 16 * r;
        int slot = t & 15;
        int f = (row & 3) | ((row & 8) >> 1);
        int cs = slot ^ f;
        ksrc[r] = Kc + (size_t)row * 1024 + kvh * 128 + cs * 8;
        kdst[r] = Kl0 + (t + 256 * r) * 8;
        int rowv = (t >> 2) + 64 * r;
        int sv = t & 3;
        vsrc[r] = Vt + (size_t)(kvh * 128 + rowv) * 2048 + sv * 8;
        vdst[r] = Vl0 + (t + 256 * r) * 8;
    }

    // ---- LDS read offsets (per-lane constants) ----
    const int rk0 = 8 * (l15 >> 2) + (l15 & 3);   // key-permuted row (s0)
    int koff[8], voff[8];
#pragma unroll
    for (int c = 0; c < 4; ++c) {
        koff[c] = kswz(rk0, quad + c * 4);
        koff[4 + c] = kswz(rk0 + 4, quad + c * 4);
    }
#pragma unroll
    for (int n = 0; n < 8; ++n) voff[n] = (n * 16 + l15) * 32 + quad * 8;

    f32x4 o[8] = {};
    float m = NEG_BIG, l = 0.f;
    const int my_nb = (q0 + 47) / 32;   // my causal key-block count (<= nbt)

    // ---- prologue: stage block 0 into buffer 0 ----
    {
        gld_lds16(kdst[0], ksrc[0]);
        gld_lds16(kdst[1], ksrc[1]);
        gld_lds16(vdst[0], vsrc[0]);
        gld_lds16(vdst[1], vsrc[1]);
    }
    __syncthreads();

    for (int ib = 0; ib < nbt; ++ib) {
        if (ib + 1 < nbt) {   // stage next block into the other buffer
            int kb = (ib + 1) * 32;
            int bo = ((ib + 1) & 1) * 4096;
            gld_lds16(kdst[0] + bo, ksrc[0] + (size_t)kb * 1024);
            gld_lds16(kdst[1] + bo, ksrc[1] + (size_t)kb * 1024);
            gld_lds16(vdst[0] + bo, vsrc[0] + kb);
            gld_lds16(vdst[1] + bo, vsrc[1] + kb);
        }
        if (ib < my_nb) {   // wave-uniform predicate
            const short* Kl = Kl0 + (ib & 1) * 4096;
            const short* Vl = Vl0 + (ib & 1) * 4096;
            if (ib == my_nb - 1)
                fa_step_lds<true>(Kl, Vl, ib * 32, q0, l15, quad, koff, voff,
                                  qf, o, m, l);
            else
                fa_step_lds<false>(Kl, Vl, ib * 32, q0, l15, quad, koff, voff,
                                   qf, o, m, l);
        }
        __syncthreads();
    }

    // epilogue: O rows are q=quad*4+r; fetch l from q=l15 lanes
    float inv[4];
#pragma unroll
    for (int r = 0; r < 4; ++r) inv[r] = 1.f / __shfl(l, quad * 20 + r);
#pragma unroll
    for (int n = 0; n < 8; ++n)
#pragma unroll
        for (int r = 0; r < 4; ++r) {
            int row = q0 + quad * 4 + r;
            O[(size_t)row * 4096 + h * 128 + n * 16 + l15] =
                f2bf(o[n][r] * inv[r]);
        }
}

__global__ __launch_bounds__(256) void flash_attn(
    const u16* __restrict__ Q, const u16* __restrict__ Kc,
    const u16* __restrict__ Vt, u16* __restrict__ O) {
    __shared__ __align__(16) short Kl[2 * 32 * 128];
    __shared__ __align__(16) short Vl[2 * 128 * 32];
    const int pp = blockIdx.x;   // 0..15  (q-tile pair: pp and 31-pp)
    const int h = blockIdx.y;    // 0..31
    const int kvh = h >> 2;
    const int t = threadIdx.x, wave = t >> 6;
    // wave w of tile pp pairs with wave 3-w of tile 31-pp: 68 lockstep
    // iterations per block, identical for every block (perfect balance)
    fa_task(Q, Kc, Vt, O, Kl, Vl, pp * 64 + wave * 16, 2 * pp + 2, h, kvh, t);
    const int tb = 31 - pp;
    fa_task(Q, Kc, Vt, O, Kl, Vl, tb * 64 + (3 - wave) * 16, 2 * tb + 2, h,
            kvh, t);
}

// ---------------------------------------------------------------------------
extern "C" void kernel_launch(void* const* d_in, const int* in_sizes, int n_in,
                              void* d_out, int out_size, void* d_ws,
                              size_t ws_size, hipStream_t stream) {
    const float* x  = (const float*)d_in[0];
    const float* wq = (const float*)d_in[1];
    const float* wk = (const float*)d_in[2];
    const float* wv = (const float*)d_in[3];
    const float* wo = (const float*)d_in[4];
    const float* fc = (const float*)d_in[5];
    const float* fs = (const float*)d_in[6];
    float* out = (float*)d_out;

    const int NX = 2048 * 4096;
    const int NQW = 4096 * 4096;
    const int NKW = 1024 * 4096;
    const int NKV = 2048 * 1024;

    u16* Q   = (u16*)d_ws;
    u16* Kc  = Q   + NX;
    u16* Vt  = Kc  + NKV;   // [1024 features][2048 seq]
    u16* Ao  = Vt  + NKV;
    u16* xb  = Ao  + NX;
    u16* wqb = xb  + NX;
    u16* wkb = wqb + NQW;
    u16* wvb = wkb + NKW;
    u16* wob = wvb + NKW;

    cvt_bf16<<<NX / (256 * 8), 256, 0, stream>>>(x, xb, NX);
    cvt_bf16<<<NQW / (256 * 8), 256, 0, stream>>>(wq, wqb, NQW);
    cvt_bf16<<<NKW / (256 * 8), 256, 0, stream>>>(wk, wkb, NKW);
    cvt_bf16<<<NKW / (256 * 8), 256, 0, stream>>>(wv, wvb, NKW);
    cvt_bf16<<<NQW / (256 * 8), 256, 0, stream>>>(wo, wob, NQW);

    qkv_proj<<<dim3(16, 48), 256, 0, stream>>>(xb, wqb, wkb, wvb, Q, Kc, Vt);
    rope_kernel<<<(2048 * 32 * 64 + 255) / 256, 256, 0, stream>>>(Q, fc, fs, 32);
    rope_kernel<<<(2048 * 8 * 64 + 255) / 256, 256, 0, stream>>>(Kc, fc, fs, 8);
    flash_attn<<<dim3(16, 32), 256, 0, stream>>>(Q, Kc, Vt, Ao);
    oproj<<<dim3(16, 32), 256, 0, stream>>>(Ao, wob, out);
}

// Round 3
// 512.456 us; speedup vs baseline: 1.7626x; 1.0419x over previous
//
#include <hip/hip_runtime.h>
#include <math.h>
#include <stdint.h>
#include <stddef.h>

// ---------------------------------------------------------------------------
// Attention layer for MI355X (gfx950). I/O fp32; internal bf16 MFMA pipeline.
//   cvt: x/wq/wk/wv/wo -> bf16
//   qkv_proj8 / oproj8: 8-phase counted-vmcnt MFMA GEMM (T3+T4+T5)
//   RoPE(Q), RoPE(K)
//   flash_attn: LDS-staged (async global_load_lds, double-buffered),
//               key-permuted S^T trick, causal, GQA rep=4, defer-max rescale
// Only mfma_f32_16x16x32_bf16 is used (HW-verified layouts m89/m97).
// ---------------------------------------------------------------------------

typedef __attribute__((ext_vector_type(8))) short bf16x8;
typedef __attribute__((ext_vector_type(4))) short bf16x4;
typedef __attribute__((ext_vector_type(4))) float f32x4;
typedef unsigned short u16;

#define NEG_BIG (-1.0e9f)
#define MFMA32(a, b, c) __builtin_amdgcn_mfma_f32_16x16x32_bf16(a, b, c, 0, 0, 0)

__device__ __forceinline__ float bf2f(u16 b) {
    return __uint_as_float(((unsigned int)b) << 16);
}
__device__ __forceinline__ u16 f2bf(float f) {
    unsigned int u = __float_as_uint(f);
    u += 0x7fff + ((u >> 16) & 1);   // RNE
    return (u16)(u >> 16);
}
__device__ __forceinline__ void gld_lds16(short* lds, const u16* g) {
    __builtin_amdgcn_global_load_lds(
        (const __attribute__((address_space(1))) void*)g,
        (__attribute__((address_space(3))) void*)lds, 16, 0, 0);
}

// ---------------------------------------------------------------------------
// fp32 -> bf16 bulk convert (n multiple of 8)
// ---------------------------------------------------------------------------
__global__ __launch_bounds__(256) void cvt_bf16(const float* __restrict__ src,
                                                u16* __restrict__ dst, int n) {
    int i = (blockIdx.x * blockDim.x + threadIdx.x) * 8;
    if (i >= n) return;
    float4 a, b;
    __builtin_memcpy(&a, src + i, 16);
    __builtin_memcpy(&b, src + i + 4, 16);
    bf16x8 o;
    o[0] = (short)f2bf(a.x); o[1] = (short)f2bf(a.y);
    o[2] = (short)f2bf(a.z); o[3] = (short)f2bf(a.w);
    o[4] = (short)f2bf(b.x); o[5] = (short)f2bf(b.y);
    o[6] = (short)f2bf(b.z); o[7] = (short)f2bf(b.w);
    __builtin_memcpy(dst + i, &o, 16);
}

// ---------------------------------------------------------------------------
// 8-phase counted-vmcnt GEMM: C = A[M,K] @ B[N,K]^T, bf16 in, fp32 accum.
//
// Tile BM x BN, BK=64, 512 threads (8 waves as 2M x 4N). Per-wave output
// (BM/2) x 64. MH = (BM/2)/64 = m-half count per wave (2 -> 8 phases/iter,
// 1 -> 4 phases/iter). Iteration = 2 K-tiles (kt even in buf0, odd in buf1).
// Phase (buf, ks, mh): ds_read frags -> stage one future half-tile via
// global_load_lds -> s_barrier -> setprio(1) 16 MFMA setprio(0) ->
// lgkmcnt(0) [+ counted vmcnt checkpoint] -> s_barrier.
//
// Half-tile = [rows][32 cols] staged at its earliest-dead phase; counted
// vmcnt + barrier makes the per-wave guarantee collective:
//   MH=2: stagger p0:b1.Ak1(JIT) p1:b1.Bk1 p2:b0.Ak0 p3:b0.Bk0 p4:b0.Ak1
//         p5:b0.Bk1 p6:b1.Ak0 p7:b1.Bk0;  vmcnt(4) at p3/p7 only.
//   MH=1: p0:b1.{A,B}k1(JIT) p1:b0.k0 p2:b0.k1 p3:b1.k0; vmcnt(6) each phase.
// Never vmcnt(0) in the main loop; final iteration peeled and drained.
// LDS stays linear (global_load_lds dest constraint); the 32-short row
// layout reads 8 lanes per 16B bank-cluster = conflict-free.
// ---------------------------------------------------------------------------

#define G8_STGA(bf_, ks_, kt_)                                               \
    {                                                                        \
        _Pragma("unroll") for (int r_ = 0; r_ < RA; ++r_)                    \
            gld_lds16(Ad + (bf_) * AT + (ks_) * AH + r_ * 4096,              \
                      Ag + gK * r_ + (size_t)(kt_) * 64 + (ks_) * 32);       \
    }
#define G8_STGB(bf_, ks_, kt_)                                               \
    {                                                                        \
        _Pragma("unroll") for (int r_ = 0; r_ < RB; ++r_)                    \
            gld_lds16(Bd + (bf_) * BT + (ks_) * BH + r_ * 4096,              \
                      Bg + gK * r_ + (size_t)(kt_) * 64 + (ks_) * 32);       \
    }
#define G8_PHASE(bf_, ks_, mh_, RDB_, STAGE_, WAIT_)                         \
    {                                                                        \
        if (RDB_) {                                                          \
            _Pragma("unroll") for (int n_ = 0; n_ < 4; ++n_)                 \
                __builtin_memcpy(&bfr[n_], Bs + (bf_) * BT + (ks_) * BH +    \
                                               bbase + n_ * 512, 16);        \
        }                                                                    \
        _Pragma("unroll") for (int i_ = 0; i_ < 4; ++i_)                     \
            __builtin_memcpy(&af[i_], S + (bf_) * AT + (ks_) * AH + abase +  \
                                          ((mh_) * 64 + i_ * 16) * 32, 16);  \
        STAGE_;                                                              \
        __builtin_amdgcn_s_barrier();                                        \
        __builtin_amdgcn_s_setprio(1);                                       \
        _Pragma("unroll") for (int i_ = 0; i_ < 4; ++i_)                     \
            _Pragma("unroll") for (int n_ = 0; n_ < 4; ++n_)                 \
                acc[(mh_) * 4 + i_][n_] =                                    \
                    MFMA32(af[i_], bfr[n_], acc[(mh_) * 4 + i_][n_]);        \
        __builtin_amdgcn_s_setprio(0);                                       \
        asm volatile("s_waitcnt lgkmcnt(0)" ::: "memory");                   \
        WAIT_;                                                               \
        __builtin_amdgcn_s_barrier();                                        \
    }

template <int BM, int BN, int MH, int OUT>
__device__ __forceinline__ void gemm8p(const u16* __restrict__ A,
                                       const u16* __restrict__ B,
                                       void* __restrict__ C,
                                       int mb, int nb, int N, int K,
                                       short* __restrict__ S) {
    constexpr int AT = BM * 64, BT = BN * 64;    // shorts per buffer tile
    constexpr int AH = BM * 32, BH = BN * 32;    // shorts per ks-half
    constexpr int RA = BM / 128, RB = BN / 128;  // gld rounds per half
    short* const Bs = S + 2 * AT;

    const int t = threadIdx.x;
    const int lane = t & 63, l15 = lane & 15, quad = lane >> 4;
    const int wid = t >> 6, wr = wid >> 2, wc = wid & 3;

    // staging: thread t, round r covers row (t>>2)+128r, 16B slot t&3
    const int srow = t >> 2, sslot = t & 3;
    const u16* const Ag = A + (size_t)(mb * BM + srow) * K + sslot * 8;
    const u16* const Bg = B + (size_t)(nb * BN + srow) * K + sslot * 8;
    short* const Ad = S + t * 8;
    short* const Bd = Bs + t * 8;
    const size_t gK = (size_t)128 * K;

    // ds-read bases (per-lane)
    const int abase = (wr * (BM / 2) + l15) * 32 + quad * 8;
    const int bbase = (wc * 64 + l15) * 32 + quad * 8;

    f32x4 acc[MH * 4][4] = {};
    bf16x8 af[4], bfr[4];

    // ---- prologue: buf0 <- tile 0 (both halves), buf1.k0 <- tile 1 ----
    G8_STGA(0, 0, 0); G8_STGB(0, 0, 0);
    G8_STGA(0, 1, 0); G8_STGB(0, 1, 0);
    G8_STGA(1, 0, 1); G8_STGB(1, 0, 1);
    if constexpr (MH == 2) {
        asm volatile("s_waitcnt vmcnt(4)" ::: "memory");
    } else {
        asm volatile("s_waitcnt vmcnt(6)" ::: "memory");
    }
    __builtin_amdgcn_s_barrier();

    const int nIt = K >> 7;   // 2 K-tiles per iteration
    if constexpr (MH == 2) {
        for (int it = 0; it < nIt; ++it) {
            const int k0 = 2 * it, k1 = k0 + 1;
            const bool nl = (it < nIt - 1);
            G8_PHASE(0, 0, 0, true,  G8_STGA(1, 1, k1), );
            G8_PHASE(0, 0, 1, false, G8_STGB(1, 1, k1), );
            G8_PHASE(0, 1, 0, true,  if (nl) G8_STGA(0, 0, k0 + 2), );
            G8_PHASE(0, 1, 1, false, if (nl) G8_STGB(0, 0, k0 + 2),
                     if (nl) { asm volatile("s_waitcnt vmcnt(4)" ::: "memory"); }
                     else    { asm volatile("s_waitcnt vmcnt(0)" ::: "memory"); });
            G8_PHASE(1, 0, 0, true,  if (nl) G8_STGA(0, 1, k0 + 2), );
            G8_PHASE(1, 0, 1, false, if (nl) G8_STGB(0, 1, k0 + 2), );
            G8_PHASE(1, 1, 0, true,  if (nl) G8_STGA(1, 0, k1 + 2), );
            G8_PHASE(1, 1, 1, false, if (nl) G8_STGB(1, 0, k1 + 2),
                     if (nl) { asm volatile("s_waitcnt vmcnt(4)" ::: "memory"); });
        }
    } else {
        for (int it = 0; it < nIt - 1; ++it) {
            const int k0 = 2 * it, k1 = k0 + 1;
            G8_PHASE(0, 0, 0, true, { G8_STGA(1, 1, k1); G8_STGB(1, 1, k1); },
                     asm volatile("s_waitcnt vmcnt(6)" ::: "memory"));
            G8_PHASE(0, 1, 0, true, { G8_STGA(0, 0, k0 + 2); G8_STGB(0, 0, k0 + 2); },
                     asm volatile("s_waitcnt vmcnt(6)" ::: "memory"));
            G8_PHASE(1, 0, 0, true, { G8_STGA(0, 1, k0 + 2); G8_STGB(0, 1, k0 + 2); },
                     asm volatile("s_waitcnt vmcnt(6)" ::: "memory"));
            G8_PHASE(1, 1, 0, true, { G8_STGA(1, 0, k1 + 2); G8_STGB(1, 0, k1 + 2); },
                     asm volatile("s_waitcnt vmcnt(6)" ::: "memory"));
        }
        {   // final iteration, peeled: drain
            const int k1 = (K >> 6) - 1;
            G8_PHASE(0, 0, 0, true, { G8_STGA(1, 1, k1); G8_STGB(1, 1, k1); },
                     asm volatile("s_waitcnt vmcnt(6)" ::: "memory"));
            G8_PHASE(0, 1, 0, true, ,
                     asm volatile("s_waitcnt vmcnt(3)" ::: "memory"));
            G8_PHASE(1, 0, 0, true, ,
                     asm volatile("s_waitcnt vmcnt(0)" ::: "memory"));
            G8_PHASE(1, 1, 0, true, , );
        }
    }

    // ---- epilogue. C/D layout: col = l15, row = quad*4 + r ----
#pragma unroll
    for (int i8 = 0; i8 < MH * 4; ++i8) {
        const int rowb = mb * BM + wr * (BM / 2) + (i8 >> 2) * 64 +
                         (i8 & 3) * 16 + quad * 4;
#pragma unroll
        for (int j = 0; j < 4; ++j) {
            const int col = nb * BN + wc * 64 + j * 16 + l15;
            if (OUT == 2) {
                // transposed write: [col][seq], 4 consecutive rows -> 8B
                bf16x4 v;
#pragma unroll
                for (int r = 0; r < 4; ++r) v[r] = (short)f2bf(acc[i8][j][r]);
                __builtin_memcpy((u16*)C + (size_t)col * 2048 + rowb, &v, 8);
            } else if (OUT == 1) {
#pragma unroll
                for (int r = 0; r < 4; ++r)
                    ((float*)C)[(size_t)(rowb + r) * N + col] = acc[i8][j][r];
            } else {
#pragma unroll
                for (int r = 0; r < 4; ++r)
                    ((u16*)C)[(size_t)(rowb + r) * N + col] =
                        f2bf(acc[i8][j][r]);
            }
        }
    }
}

__global__ __launch_bounds__(512, 2) void qkv_proj8(
    const u16* __restrict__ x,
    const u16* __restrict__ wq, const u16* __restrict__ wk,
    const u16* __restrict__ wv,
    u16* __restrict__ Q, u16* __restrict__ Kc, u16* __restrict__ Vt) {
    __shared__ __align__(16) short S[65536];   // 128 KiB
    const int mb = blockIdx.x, y = blockIdx.y;
    if (y < 16)
        gemm8p<256, 256, 2, 0>(x, wq, Q, mb, y, 4096, 4096, S);
    else if (y < 20)
        gemm8p<256, 256, 2, 0>(x, wk, Kc, mb, y - 16, 1024, 4096, S);
    else
        gemm8p<256, 256, 2, 2>(x, wv, Vt, mb, y - 20, 1024, 4096, S);
}

__global__ __launch_bounds__(512, 2) void oproj8(
    const u16* __restrict__ A, const u16* __restrict__ wo,
    float* __restrict__ out) {
    __shared__ __align__(16) short S[49152];   // 96 KiB
    gemm8p<128, 256, 1, 1>(A, wo, out, blockIdx.x, blockIdx.y, 4096, 4096, S);
}

// ---------------------------------------------------------------------------
// RoPE in-place: X viewed as (2048, nheads, 64 pairs of 2); cos/sin fp32
// ---------------------------------------------------------------------------
__global__ void rope_kernel(u16* __restrict__ X,
                            const float* __restrict__ cosb,
                            const float* __restrict__ sinb, int nheads) {
    int idx = blockIdx.x * blockDim.x + threadIdx.x;
    int total = 2048 * nheads * 64;
    if (idx >= total) return;
    int i = idx % 64;
    int h = (idx / 64) % nheads;
    int s = idx / (64 * nheads);
    u16* p = X + (size_t)s * nheads * 128 + h * 128 + 2 * i;
    float x0 = bf2f(p[0]), x1 = bf2f(p[1]);
    float c = cosb[s * 64 + i], sn = sinb[s * 64 + i];
    p[0] = f2bf(x0 * c - x1 * sn);
    p[1] = f2bf(x0 * sn + x1 * c);
}

// ---------------------------------------------------------------------------
// Flash attention, LDS-staged (2-phase global_load_lds pipeline, dbuf).
// K tile [32 keys][128 dims] XOR-swizzled 16B slots; V tile [128 feats][32]
// linear. Key-permuted S^T trick; online softmax with defer-max THR=8.
// ---------------------------------------------------------------------------
__device__ __forceinline__ int kswz(int row, int cs) {
    int f = (row & 3) | ((row & 8) >> 1);
    return row * 128 + ((cs ^ f) << 3);
}

template <bool MASKED>
__device__ __forceinline__ void fa_step_lds(
    const short* __restrict__ Kl, const short* __restrict__ Vl,
    int kb, int q0, int l15, int quad,
    const int (&koff)[8], const int (&voff)[8],
    const bf16x8 (&qf)[4], f32x4 (&o)[8], float& m, float& l) {
    const float scale = 0.08838834764831845f;  // 1/sqrt(128)

    // K frags from LDS (swizzled) + S^T = K.Q^T
    bf16x8 kf[8];
#pragma unroll
    for (int i = 0; i < 8; ++i) __builtin_memcpy(&kf[i], Kl + koff[i], 16);
    f32x4 s0 = {0, 0, 0, 0}, s1 = {0, 0, 0, 0};
#pragma unroll
    for (int c = 0; c < 4; ++c) {
        s0 = MFMA32(kf[c], qf[c], s0);
        s1 = MFMA32(kf[4 + c], qf[c], s1);
    }

    // V frags early: ds_read latency hides under softmax
    bf16x8 vf[8];
#pragma unroll
    for (int n = 0; n < 8; ++n) __builtin_memcpy(&vf[n], Vl + voff[n], 16);

    // scale + causal mask. Lane (quad,l15): s0[r] = key kb+8*quad+r,
    // s1[r] = key kb+8*quad+4+r, q column = l15.
    float sv0[4], sv1[4];
    const int q = q0 + l15;
#pragma unroll
    for (int r = 0; r < 4; ++r) {
        sv0[r] = s0[r] * scale;
        sv1[r] = s1[r] * scale;
        if (MASKED) {
            if (kb + 8 * quad + r > q) sv0[r] = NEG_BIG;
            if (kb + 8 * quad + 4 + r > q) sv1[r] = NEG_BIG;
        }
    }

    // online softmax: all 32 keys of q-col l15 spread across quads
    float mx = fmaxf(fmaxf(fmaxf(sv0[0], sv0[1]), fmaxf(sv0[2], sv0[3])),
                     fmaxf(fmaxf(sv1[0], sv1[1]), fmaxf(sv1[2], sv1[3])));
    mx = fmaxf(mx, __shfl_xor(mx, 16));
    mx = fmaxf(mx, __shfl_xor(mx, 32));

    // defer-max: only rescale O when the max grew past the threshold
    float alpha = 1.0f;
    if (!__all(mx <= m + 8.0f)) {
        float mnew = fmaxf(m, mx);
        alpha = __expf(m - mnew);
        float aO[4];
#pragma unroll
        for (int r = 0; r < 4; ++r) aO[r] = __shfl(alpha, quad * 20 + r);
#pragma unroll
        for (int n = 0; n < 8; ++n)
#pragma unroll
            for (int r = 0; r < 4; ++r) o[n][r] *= aO[r];
        m = mnew;
    }

    float p0[4], p1[4], sum = 0.f;
#pragma unroll
    for (int r = 0; r < 4; ++r) {
        p0[r] = __expf(sv0[r] - m);
        p1[r] = __expf(sv1[r] - m);
        sum += p0[r] + p1[r];
    }
    sum += __shfl_xor(sum, 16);
    sum += __shfl_xor(sum, 32);
    l = l * alpha + sum;

    // pack P into the 16x16x32 A-frag: element j = key 8*quad+j (zero move)
    bf16x8 pa;
#pragma unroll
    for (int r = 0; r < 4; ++r) {
        pa[r] = (short)f2bf(p0[r]);
        pa[4 + r] = (short)f2bf(p1[r]);
    }

    // O += P.V
#pragma unroll
    for (int n = 0; n < 8; ++n) o[n] = MFMA32(pa, vf[n], o[n]);
}

__device__ __forceinline__ void fa_task(
    const u16* __restrict__ Q, const u16* __restrict__ Kc,
    const u16* __restrict__ Vt, u16* __restrict__ O,
    short* __restrict__ Kl0, short* __restrict__ Vl0,
    int q0, int nbt, int h, int kvh, int t) {
    const int lane = t & 63;
    const int l15 = lane & 15, quad = lane >> 4;

    // Q B-frags (n=q=l15, k=d chunks)
    bf16x8 qf[4];
    const u16* qp = Q + (size_t)(q0 + l15) * 4096 + h * 128 + quad * 8;
#pragma unroll
    for (int c = 0; c < 4; ++c) __builtin_memcpy(&qf[c], qp + c * 32, 16);

    // ---- staging addresses (per-thread constants) ----
    const u16* ksrc[2]; short* kdst[2];
    const u16* vsrc[2]; short* vdst[2];
#pragma unroll
    for (int r = 0; r < 2; ++r) {
        int row = (t >> 4) + 16 * r;
        int slot = t & 15;
        int f = (row & 3) | ((row & 8) >> 1);
        int cs = slot ^ f;
        ksrc[r] = Kc + (size_t)row * 1024 + kvh * 128 + cs * 8;
        kdst[r] = Kl0 + (t + 256 * r) * 8;
        int rowv = (t >> 2) + 64 * r;
        int sv = t & 3;
        vsrc[r] = Vt + (size_t)(kvh * 128 + rowv) * 2048 + sv * 8;
        vdst[r] = Vl0 + (t + 256 * r) * 8;
    }

    // ---- LDS read offsets (per-lane constants) ----
    const int rk0 = 8 * (l15 >> 2) + (l15 & 3);   // key-permuted row (s0)
    int koff[8], voff[8];
#pragma unroll
    for (int c = 0; c < 4; ++c) {
        koff[c] = kswz(rk0, quad + c * 4);
        koff[4 + c] = kswz(rk0 + 4, quad + c * 4);
    }
#pragma unroll
    for (int n = 0; n < 8; ++n) voff[n] = (n * 16 + l15) * 32 + quad * 8;

    f32x4 o[8] = {};
    float m = NEG_BIG, l = 0.f;
    const int my_nb = (q0 + 47) / 32;   // my causal key-block count (<= nbt)

    // ---- prologue: stage block 0 into buffer 0 ----
    {
        gld_lds16(kdst[0], ksrc[0]);
        gld_lds16(kdst[1], ksrc[1]);
        gld_lds16(vdst[0], vsrc[0]);
        gld_lds16(vdst[1], vsrc[1]);
    }
    __syncthreads();

    for (int ib = 0; ib < nbt; ++ib) {
        if (ib + 1 < nbt) {   // stage next block into the other buffer
            int kb = (ib + 1) * 32;
            int bo = ((ib + 1) & 1) * 4096;
            gld_lds16(kdst[0] + bo, ksrc[0] + (size_t)kb * 1024);
            gld_lds16(kdst[1] + bo, ksrc[1] + (size_t)kb * 1024);
            gld_lds16(vdst[0] + bo, vsrc[0] + kb);
            gld_lds16(vdst[1] + bo, vsrc[1] + kb);
        }
        if (ib < my_nb) {   // wave-uniform predicate
            const short* Kl = Kl0 + (ib & 1) * 4096;
            const short* Vl = Vl0 + (ib & 1) * 4096;
            if (ib == my_nb - 1)
                fa_step_lds<true>(Kl, Vl, ib * 32, q0, l15, quad, koff, voff,
                                  qf, o, m, l);
            else
                fa_step_lds<false>(Kl, Vl, ib * 32, q0, l15, quad, koff, voff,
                                   qf, o, m, l);
        }
        __syncthreads();
    }

    // epilogue: O rows are q=quad*4+r; fetch l from q=l15 lanes
    float inv[4];
#pragma unroll
    for (int r = 0; r < 4; ++r) inv[r] = 1.f / __shfl(l, quad * 20 + r);
#pragma unroll
    for (int n = 0; n < 8; ++n)
#pragma unroll
        for (int r = 0; r < 4; ++r) {
            int row = q0 + quad * 4 + r;
            O[(size_t)row * 4096 + h * 128 + n * 16 + l15] =
                f2bf(o[n][r] * inv[r]);
        }
}

__global__ __launch_bounds__(256) void flash_attn(
    const u16* __restrict__ Q, const u16* __restrict__ Kc,
    const u16* __restrict__ Vt, u16* __restrict__ O) {
    __shared__ __align__(16) short Kl[2 * 32 * 128];
    __shared__ __align__(16) short Vl[2 * 128 * 32];
    const int pp = blockIdx.x;   // 0..15  (q-tile pair: pp and 31-pp)
    const int h = blockIdx.y;    // 0..31
    const int kvh = h >> 2;
    const int t = threadIdx.x, wave = t >> 6;
    // wave w of tile pp pairs with wave 3-w of tile 31-pp: 68 lockstep
    // iterations per block, identical for every block (perfect balance)
    fa_task(Q, Kc, Vt, O, Kl, Vl, pp * 64 + wave * 16, 2 * pp + 2, h, kvh, t);
    const int tb = 31 - pp;
    fa_task(Q, Kc, Vt, O, Kl, Vl, tb * 64 + (3 - wave) * 16, 2 * tb + 2, h,
            kvh, t);
}

// ---------------------------------------------------------------------------
extern "C" void kernel_launch(void* const* d_in, const int* in_sizes, int n_in,
                              void* d_out, int out_size, void* d_ws,
                              size_t ws_size, hipStream_t stream) {
    const float* x  = (const float*)d_in[0];
    const float* wq = (const float*)d_in[1];
    const float* wk = (const float*)d_in[2];
    const float* wv = (const float*)d_in[3];
    const float* wo = (const float*)d_in[4];
    const float* fc = (const float*)d_in[5];
    const float* fs = (const float*)d_in[6];
    float* out = (float*)d_out;

    const int NX = 2048 * 4096;
    const int NQW = 4096 * 4096;
    const int NKW = 1024 * 4096;
    const int NKV = 2048 * 1024;

    u16* Q   = (u16*)d_ws;
    u16* Kc  = Q   + NX;
    u16* Vt  = Kc  + NKV;   // [1024 features][2048 seq]
    u16* Ao  = Vt  + NKV;
    u16* xb  = Ao  + NX;
    u16* wqb = xb  + NX;
    u16* wkb = wqb + NQW;
    u16* wvb = wkb + NKW;
    u16* wob = wvb + NKW;

    cvt_bf16<<<NX / (256 * 8), 256, 0, stream>>>(x, xb, NX);
    cvt_bf16<<<NQW / (256 * 8), 256, 0, stream>>>(wq, wqb, NQW);
    cvt_bf16<<<NKW / (256 * 8), 256, 0, stream>>>(wk, wkb, NKW);
    cvt_bf16<<<NKW / (256 * 8), 256, 0, stream>>>(wv, wvb, NKW);
    cvt_bf16<<<NQW / (256 * 8), 256, 0, stream>>>(wo, wob, NQW);

    qkv_proj8<<<dim3(8, 24), 512, 0, stream>>>(xb, wqb, wkb, wvb, Q, Kc, Vt);
    rope_kernel<<<(2048 * 32 * 64 + 255) / 256, 256, 0, stream>>>(Q, fc, fs, 32);
    rope_kernel<<<(2048 * 8 * 64 + 255) / 256, 256, 0, stream>>>(Kc, fc, fs, 8);
    flash_attn<<<dim3(16, 32), 256, 0, stream>>>(Q, Kc, Vt, Ao);
    oproj8<<<dim3(16, 16), 512, 0, stream>>>(Ao, wob, out);
}

// Round 4
// 500.227 us; speedup vs baseline: 1.8056x; 1.0244x over previous
//
#include <hip/hip_runtime.h>
#include <math.h>
#include <stdint.h>
#include <stddef.h>

// ---------------------------------------------------------------------------
// Attention layer for MI355X (gfx950). I/O fp32; internal bf16 MFMA pipeline.
//   cvt: x/wq/wk/wv/wo -> bf16
//   qkv_proj8 / oproj8: 8-phase counted-vmcnt MFMA GEMM (T3+T4+T5) with
//       T2 XOR bank-swizzle on both LDS tiles (s = quad ^ ((row>>1)&3))
//   RoPE(Q), RoPE(K)
//   flash_attn: LDS-staged (async global_load_lds, double-buffered),
//               key-permuted S^T trick, causal, GQA rep=4, defer-max rescale
// Only mfma_f32_16x16x32_bf16 is used (HW-verified layouts m89/m97).
// ---------------------------------------------------------------------------

typedef __attribute__((ext_vector_type(8))) short bf16x8;
typedef __attribute__((ext_vector_type(4))) short bf16x4;
typedef __attribute__((ext_vector_type(4))) float f32x4;
typedef unsigned short u16;

#define NEG_BIG (-1.0e9f)
#define MFMA32(a, b, c) __builtin_amdgcn_mfma_f32_16x16x32_bf16(a, b, c, 0, 0, 0)

__device__ __forceinline__ float bf2f(u16 b) {
    return __uint_as_float(((unsigned int)b) << 16);
}
__device__ __forceinline__ u16 f2bf(float f) {
    unsigned int u = __float_as_uint(f);
    u += 0x7fff + ((u >> 16) & 1);   // RNE
    return (u16)(u >> 16);
}
__device__ __forceinline__ void gld_lds16(short* lds, const u16* g) {
    __builtin_amdgcn_global_load_lds(
        (const __attribute__((address_space(1))) void*)g,
        (__attribute__((address_space(3))) void*)lds, 16, 0, 0);
}

// ---------------------------------------------------------------------------
// fp32 -> bf16 bulk convert (n multiple of 8)
// ---------------------------------------------------------------------------
__global__ __launch_bounds__(256) void cvt_bf16(const float* __restrict__ src,
                                                u16* __restrict__ dst, int n) {
    int i = (blockIdx.x * blockDim.x + threadIdx.x) * 8;
    if (i >= n) return;
    float4 a, b;
    __builtin_memcpy(&a, src + i, 16);
    __builtin_memcpy(&b, src + i + 4, 16);
    bf16x8 o;
    o[0] = (short)f2bf(a.x); o[1] = (short)f2bf(a.y);
    o[2] = (short)f2bf(a.z); o[3] = (short)f2bf(a.w);
    o[4] = (short)f2bf(b.x); o[5] = (short)f2bf(b.y);
    o[6] = (short)f2bf(b.z); o[7] = (short)f2bf(b.w);
    __builtin_memcpy(dst + i, &o, 16);
}

// ---------------------------------------------------------------------------
// 8-phase counted-vmcnt GEMM: C = A[M,K] @ B[N,K]^T, bf16 in, fp32 accum.
//
// Tile BM x BN, BK=64, 512 threads (8 waves as 2M x 4N). Per-wave output
// (BM/2) x 64. MH = (BM/2)/64 = m-half count per wave (2 -> 8 phases/iter,
// 1 -> 4 phases/iter). Iteration = 2 K-tiles (kt even in buf0, odd in buf1).
// Phase: ds_read frags -> stage one future half-tile via global_load_lds ->
// s_barrier -> lgkmcnt(0) -> setprio(1) 16 MFMA setprio(0) ->
// [counted vmcnt checkpoint] -> s_barrier.  (m201 template ordering)
//
// T2 bank swizzle: LDS tile = [rows][4 slots of 16B] (64B rows). Unswizzled,
// a quarter-wave's 16 rows hit granule (row*4+quad)%8 = only 2 positions ->
// 8-way conflict (measured 9.4e6/dispatch in r3). Read slot
// s = quad ^ ((row>>1)&3) spreads 16 rows over all 8 positions, 2 lanes
// each = wave minimum (free). Since row = l15 (mod 16) at every read site,
// the swizzle folds into the per-lane base. global_load_lds writes LDS
// linearly, so the inverse permutation is baked into the per-lane GLOBAL
// source slot: cs = (t&3) ^ ((t>>3)&3)  (round-invariant).
//
// Stagger (earliest-dead-phase staging; counted vmcnt + barrier makes the
// per-wave count a collective guarantee):
//   MH=2: p0:b1.Ak1(JIT) p1:b1.Bk1 p2:b0.Ak0 p3:b0.Bk0 p4:b0.Ak1
//         p5:b0.Bk1 p6:b1.Ak0 p7:b1.Bk0;  vmcnt(4) at p3/p7 only.
//   MH=1: p0:b1.{A,B}k1(JIT) p1:b0.k0 p2:b0.k1 p3:b1.k0; vmcnt(6) each phase.
// Never vmcnt(0) in the main loop; final iteration peeled and drained.
// ---------------------------------------------------------------------------

#define G8_STGA(bf_, ks_, kt_)                                               \
    {                                                                        \
        _Pragma("unroll") for (int r_ = 0; r_ < RA; ++r_)                    \
            gld_lds16(Ad + (bf_) * AT + (ks_) * AH + r_ * 4096,              \
                      Ag + gK * r_ + (size_t)(kt_) * 64 + (ks_) * 32);       \
    }
#define G8_STGB(bf_, ks_, kt_)                                               \
    {                                                                        \
        _Pragma("unroll") for (int r_ = 0; r_ < RB; ++r_)                    \
            gld_lds16(Bd + (bf_) * BT + (ks_) * BH + r_ * 4096,              \
                      Bg + gK * r_ + (size_t)(kt_) * 64 + (ks_) * 32);       \
    }
#define G8_PHASE(bf_, ks_, mh_, RDB_, STAGE_, WAIT_)                         \
    {                                                                        \
        if (RDB_) {                                                          \
            _Pragma("unroll") for (int n_ = 0; n_ < 4; ++n_)                 \
                __builtin_memcpy(&bfr[n_], Bs + (bf_) * BT + (ks_) * BH +    \
                                               bbase + n_ * 512, 16);        \
        }                                                                    \
        _Pragma("unroll") for (int i_ = 0; i_ < 4; ++i_)                     \
            __builtin_memcpy(&af[i_], S + (bf_) * AT + (ks_) * AH + abase +  \
                                          ((mh_) * 64 + i_ * 16) * 32, 16);  \
        STAGE_;                                                              \
        __builtin_amdgcn_s_barrier();                                        \
        asm volatile("s_waitcnt lgkmcnt(0)" ::: "memory");                   \
        __builtin_amdgcn_s_setprio(1);                                       \
        _Pragma("unroll") for (int i_ = 0; i_ < 4; ++i_)                     \
            _Pragma("unroll") for (int n_ = 0; n_ < 4; ++n_)                 \
                acc[(mh_) * 4 + i_][n_] =                                    \
                    MFMA32(af[i_], bfr[n_], acc[(mh_) * 4 + i_][n_]);        \
        __builtin_amdgcn_s_setprio(0);                                       \
        WAIT_;                                                               \
        __builtin_amdgcn_s_barrier();                                        \
    }

template <int BM, int BN, int MH, int OUT>
__device__ __forceinline__ void gemm8p(const u16* __restrict__ A,
                                       const u16* __restrict__ B,
                                       void* __restrict__ C,
                                       int mb, int nb, int N, int K,
                                       short* __restrict__ S) {
    constexpr int AT = BM * 64, BT = BN * 64;    // shorts per buffer tile
    constexpr int AH = BM * 32, BH = BN * 32;    // shorts per ks-half
    constexpr int RA = BM / 128, RB = BN / 128;  // gld rounds per half
    short* const Bs = S + 2 * AT;

    const int t = threadIdx.x;
    const int lane = t & 63, l15 = lane & 15, quad = lane >> 4;
    const int wid = t >> 6, wr = wid >> 2, wc = wid & 3;

    // staging: thread t, round r covers row (t>>2)+128r; LDS slot t&3 holds
    // global slot cs (inverse of the read swizzle)
    const int srow = t >> 2;
    const int cs = (t & 3) ^ ((t >> 3) & 3);
    const u16* const Ag = A + (size_t)(mb * BM + srow) * K + cs * 8;
    const u16* const Bg = B + (size_t)(nb * BN + srow) * K + cs * 8;
    short* const Ad = S + t * 8;
    short* const Bd = Bs + t * 8;
    const size_t gK = (size_t)128 * K;

    // ds-read bases (per-lane), T2-swizzled slot
    const int swz = (quad ^ ((l15 >> 1) & 3)) * 8;
    const int abase = (wr * (BM / 2) + l15) * 32 + swz;
    const int bbase = (wc * 64 + l15) * 32 + swz;

    f32x4 acc[MH * 4][4] = {};
    bf16x8 af[4], bfr[4];

    // ---- prologue: buf0 <- tile 0 (both halves), buf1.k0 <- tile 1 ----
    G8_STGA(0, 0, 0); G8_STGB(0, 0, 0);
    G8_STGA(0, 1, 0); G8_STGB(0, 1, 0);
    G8_STGA(1, 0, 1); G8_STGB(1, 0, 1);
    if constexpr (MH == 2) {
        asm volatile("s_waitcnt vmcnt(4)" ::: "memory");
    } else {
        asm volatile("s_waitcnt vmcnt(6)" ::: "memory");
    }
    __builtin_amdgcn_s_barrier();

    const int nIt = K >> 7;   // 2 K-tiles per iteration
    if constexpr (MH == 2) {
        for (int it = 0; it < nIt; ++it) {
            const int k0 = 2 * it, k1 = k0 + 1;
            const bool nl = (it < nIt - 1);
            G8_PHASE(0, 0, 0, true,  G8_STGA(1, 1, k1), );
            G8_PHASE(0, 0, 1, false, G8_STGB(1, 1, k1), );
            G8_PHASE(0, 1, 0, true,  if (nl) G8_STGA(0, 0, k0 + 2), );
            G8_PHASE(0, 1, 1, false, if (nl) G8_STGB(0, 0, k0 + 2),
                     if (nl) { asm volatile("s_waitcnt vmcnt(4)" ::: "memory"); }
                     else    { asm volatile("s_waitcnt vmcnt(0)" ::: "memory"); });
            G8_PHASE(1, 0, 0, true,  if (nl) G8_STGA(0, 1, k0 + 2), );
            G8_PHASE(1, 0, 1, false, if (nl) G8_STGB(0, 1, k0 + 2), );
            G8_PHASE(1, 1, 0, true,  if (nl) G8_STGA(1, 0, k1 + 2), );
            G8_PHASE(1, 1, 1, false, if (nl) G8_STGB(1, 0, k1 + 2),
                     if (nl) { asm volatile("s_waitcnt vmcnt(4)" ::: "memory"); });
        }
    } else {
        for (int it = 0; it < nIt - 1; ++it) {
            const int k0 = 2 * it, k1 = k0 + 1;
            G8_PHASE(0, 0, 0, true, { G8_STGA(1, 1, k1); G8_STGB(1, 1, k1); },
                     asm volatile("s_waitcnt vmcnt(6)" ::: "memory"));
            G8_PHASE(0, 1, 0, true, { G8_STGA(0, 0, k0 + 2); G8_STGB(0, 0, k0 + 2); },
                     asm volatile("s_waitcnt vmcnt(6)" ::: "memory"));
            G8_PHASE(1, 0, 0, true, { G8_STGA(0, 1, k0 + 2); G8_STGB(0, 1, k0 + 2); },
                     asm volatile("s_waitcnt vmcnt(6)" ::: "memory"));
            G8_PHASE(1, 1, 0, true, { G8_STGA(1, 0, k1 + 2); G8_STGB(1, 0, k1 + 2); },
                     asm volatile("s_waitcnt vmcnt(6)" ::: "memory"));
        }
        {   // final iteration, peeled: drain
            const int k1 = (K >> 6) - 1;
            G8_PHASE(0, 0, 0, true, { G8_STGA(1, 1, k1); G8_STGB(1, 1, k1); },
                     asm volatile("s_waitcnt vmcnt(6)" ::: "memory"));
            G8_PHASE(0, 1, 0, true, ,
                     asm volatile("s_waitcnt vmcnt(3)" ::: "memory"));
            G8_PHASE(1, 0, 0, true, ,
                     asm volatile("s_waitcnt vmcnt(0)" ::: "memory"));
            G8_PHASE(1, 1, 0, true, , );
        }
    }

    // ---- epilogue. C/D layout: col = l15, row = quad*4 + r ----
#pragma unroll
    for (int i8 = 0; i8 < MH * 4; ++i8) {
        const int rowb = mb * BM + wr * (BM / 2) + (i8 >> 2) * 64 +
                         (i8 & 3) * 16 + quad * 4;
#pragma unroll
        for (int j = 0; j < 4; ++j) {
            const int col = nb * BN + wc * 64 + j * 16 + l15;
            if (OUT == 2) {
                // transposed write: [col][seq], 4 consecutive rows -> 8B
                bf16x4 v;
#pragma unroll
                for (int r = 0; r < 4; ++r) v[r] = (short)f2bf(acc[i8][j][r]);
                __builtin_memcpy((u16*)C + (size_t)col * 2048 + rowb, &v, 8);
            } else if (OUT == 1) {
#pragma unroll
                for (int r = 0; r < 4; ++r)
                    ((float*)C)[(size_t)(rowb + r) * N + col] = acc[i8][j][r];
            } else {
#pragma unroll
                for (int r = 0; r < 4; ++r)
                    ((u16*)C)[(size_t)(rowb + r) * N + col] =
                        f2bf(acc[i8][j][r]);
            }
        }
    }
}

__global__ __launch_bounds__(512, 2) void qkv_proj8(
    const u16* __restrict__ x,
    const u16* __restrict__ wq, const u16* __restrict__ wk,
    const u16* __restrict__ wv,
    u16* __restrict__ Q, u16* __restrict__ Kc, u16* __restrict__ Vt) {
    __shared__ __align__(16) short S[65536];   // 128 KiB
    const int mb = blockIdx.x, y = blockIdx.y;
    if (y < 16)
        gemm8p<256, 256, 2, 0>(x, wq, Q, mb, y, 4096, 4096, S);
    else if (y < 20)
        gemm8p<256, 256, 2, 0>(x, wk, Kc, mb, y - 16, 1024, 4096, S);
    else
        gemm8p<256, 256, 2, 2>(x, wv, Vt, mb, y - 20, 1024, 4096, S);
}

__global__ __launch_bounds__(512, 2) void oproj8(
    const u16* __restrict__ A, const u16* __restrict__ wo,
    float* __restrict__ out) {
    __shared__ __align__(16) short S[49152];   // 96 KiB
    gemm8p<128, 256, 1, 1>(A, wo, out, blockIdx.x, blockIdx.y, 4096, 4096, S);
}

// ---------------------------------------------------------------------------
// RoPE in-place: X viewed as (2048, nheads, 64 pairs of 2); cos/sin fp32
// ---------------------------------------------------------------------------
__global__ void rope_kernel(u16* __restrict__ X,
                            const float* __restrict__ cosb,
                            const float* __restrict__ sinb, int nheads) {
    int idx = blockIdx.x * blockDim.x + threadIdx.x;
    int total = 2048 * nheads * 64;
    if (idx >= total) return;
    int i = idx % 64;
    int h = (idx / 64) % nheads;
    int s = idx / (64 * nheads);
    u16* p = X + (size_t)s * nheads * 128 + h * 128 + 2 * i;
    float x0 = bf2f(p[0]), x1 = bf2f(p[1]);
    float c = cosb[s * 64 + i], sn = sinb[s * 64 + i];
    p[0] = f2bf(x0 * c - x1 * sn);
    p[1] = f2bf(x0 * sn + x1 * c);
}

// ---------------------------------------------------------------------------
// Flash attention, LDS-staged (2-phase global_load_lds pipeline, dbuf).
// K tile [32 keys][128 dims] XOR-swizzled 16B slots (2-way, free);
// V tile [128 feats][32 keys] with T2 slot swizzle quad ^ ((row>>1)&3)
// (was 8-way conflicted). Key-permuted S^T trick; online softmax with
// defer-max THR=8.
// ---------------------------------------------------------------------------
__device__ __forceinline__ int kswz(int row, int cs) {
    int f = (row & 3) | ((row & 8) >> 1);
    return row * 128 + ((cs ^ f) << 3);
}

template <bool MASKED>
__device__ __forceinline__ void fa_step_lds(
    const short* __restrict__ Kl, const short* __restrict__ Vl,
    int kb, int q0, int l15, int quad,
    const int (&koff)[8], const int (&voff)[8],
    const bf16x8 (&qf)[4], f32x4 (&o)[8], float& m, float& l) {
    const float scale = 0.08838834764831845f;  // 1/sqrt(128)

    // K frags from LDS (swizzled) + S^T = K.Q^T
    bf16x8 kf[8];
#pragma unroll
    for (int i = 0; i < 8; ++i) __builtin_memcpy(&kf[i], Kl + koff[i], 16);
    f32x4 s0 = {0, 0, 0, 0}, s1 = {0, 0, 0, 0};
#pragma unroll
    for (int c = 0; c < 4; ++c) {
        s0 = MFMA32(kf[c], qf[c], s0);
        s1 = MFMA32(kf[4 + c], qf[c], s1);
    }

    // V frags early: ds_read latency hides under softmax
    bf16x8 vf[8];
#pragma unroll
    for (int n = 0; n < 8; ++n) __builtin_memcpy(&vf[n], Vl + voff[n], 16);

    // scale + causal mask. Lane (quad,l15): s0[r] = key kb+8*quad+r,
    // s1[r] = key kb+8*quad+4+r, q column = l15.
    float sv0[4], sv1[4];
    const int q = q0 + l15;
#pragma unroll
    for (int r = 0; r < 4; ++r) {
        sv0[r] = s0[r] * scale;
        sv1[r] = s1[r] * scale;
        if (MASKED) {
            if (kb + 8 * quad + r > q) sv0[r] = NEG_BIG;
            if (kb + 8 * quad + 4 + r > q) sv1[r] = NEG_BIG;
        }
    }

    // online softmax: all 32 keys of q-col l15 spread across quads
    float mx = fmaxf(fmaxf(fmaxf(sv0[0], sv0[1]), fmaxf(sv0[2], sv0[3])),
                     fmaxf(fmaxf(sv1[0], sv1[1]), fmaxf(sv1[2], sv1[3])));
    mx = fmaxf(mx, __shfl_xor(mx, 16));
    mx = fmaxf(mx, __shfl_xor(mx, 32));

    // defer-max: only rescale O when the max grew past the threshold
    float alpha = 1.0f;
    if (!__all(mx <= m + 8.0f)) {
        float mnew = fmaxf(m, mx);
        alpha = __expf(m - mnew);
        float aO[4];
#pragma unroll
        for (int r = 0; r < 4; ++r) aO[r] = __shfl(alpha, quad * 20 + r);
#pragma unroll
        for (int n = 0; n < 8; ++n)
#pragma unroll
            for (int r = 0; r < 4; ++r) o[n][r] *= aO[r];
        m = mnew;
    }

    float p0[4], p1[4], sum = 0.f;
#pragma unroll
    for (int r = 0; r < 4; ++r) {
        p0[r] = __expf(sv0[r] - m);
        p1[r] = __expf(sv1[r] - m);
        sum += p0[r] + p1[r];
    }
    sum += __shfl_xor(sum, 16);
    sum += __shfl_xor(sum, 32);
    l = l * alpha + sum;

    // pack P into the 16x16x32 A-frag: element j = key 8*quad+j (zero move)
    bf16x8 pa;
#pragma unroll
    for (int r = 0; r < 4; ++r) {
        pa[r] = (short)f2bf(p0[r]);
        pa[4 + r] = (short)f2bf(p1[r]);
    }

    // O += P.V
#pragma unroll
    for (int n = 0; n < 8; ++n) o[n] = MFMA32(pa, vf[n], o[n]);
}

__device__ __forceinline__ void fa_task(
    const u16* __restrict__ Q, const u16* __restrict__ Kc,
    const u16* __restrict__ Vt, u16* __restrict__ O,
    short* __restrict__ Kl0, short* __restrict__ Vl0,
    int q0, int nbt, int h, int kvh, int t) {
    const int lane = t & 63;
    const int l15 = lane & 15, quad = lane >> 4;

    // Q B-frags (n=q=l15, k=d chunks)
    bf16x8 qf[4];
    const u16* qp = Q + (size_t)(q0 + l15) * 4096 + h * 128 + quad * 8;
#pragma unroll
    for (int c = 0; c < 4; ++c) __builtin_memcpy(&qf[c], qp + c * 32, 16);

    // ---- staging addresses (per-thread constants) ----
    const u16* ksrc[2]; short* kdst[2];
    const u16* vsrc[2]; short* vdst[2];
#pragma unroll
    for (int r = 0; r < 2; ++r) {
        int row = (t >> 4) + 16 * r;
        int slot = t & 15;
        int f = (row & 3) | ((row & 8) >> 1);
        int cks = slot ^ f;
        ksrc[r] = Kc + (size_t)row * 1024 + kvh * 128 + cks * 8;
        kdst[r] = Kl0 + (t + 256 * r) * 8;
        int rowv = (t >> 2) + 64 * r;
        int csv = (t & 3) ^ ((t >> 3) & 3);   // inverse of V read swizzle
        vsrc[r] = Vt + (size_t)(kvh * 128 + rowv) * 2048 + csv * 8;
        vdst[r] = Vl0 + (t + 256 * r) * 8;
    }

    // ---- LDS read offsets (per-lane constants) ----
    const int rk0 = 8 * (l15 >> 2) + (l15 & 3);   // key-permuted row (s0)
    int koff[8], voff[8];
#pragma unroll
    for (int c = 0; c < 4; ++c) {
        koff[c] = kswz(rk0, quad + c * 4);
        koff[4 + c] = kswz(rk0 + 4, quad + c * 4);
    }
    const int vswz = (quad ^ ((l15 >> 1) & 3)) * 8;
#pragma unroll
    for (int n = 0; n < 8; ++n) voff[n] = (n * 16 + l15) * 32 + vswz;

    f32x4 o[8] = {};
    float m = NEG_BIG, l = 0.f;
    const int my_nb = (q0 + 47) / 32;   // my causal key-block count (<= nbt)

    // ---- prologue: stage block 0 into buffer 0 ----
    {
        gld_lds16(kdst[0], ksrc[0]);
        gld_lds16(kdst[1], ksrc[1]);
        gld_lds16(vdst[0], vsrc[0]);
        gld_lds16(vdst[1], vsrc[1]);
    }
    __syncthreads();

    for (int ib = 0; ib < nbt; ++ib) {
        if (ib + 1 < nbt) {   // stage next block into the other buffer
            int kb = (ib + 1) * 32;
            int bo = ((ib + 1) & 1) * 4096;
            gld_lds16(kdst[0] + bo, ksrc[0] + (size_t)kb * 1024);
            gld_lds16(kdst[1] + bo, ksrc[1] + (size_t)kb * 1024);
            gld_lds16(vdst[0] + bo, vsrc[0] + kb);
            gld_lds16(vdst[1] + bo, vsrc[1] + kb);
        }
        if (ib < my_nb) {   // wave-uniform predicate
            const short* Kl = Kl0 + (ib & 1) * 4096;
            const short* Vl = Vl0 + (ib & 1) * 4096;
            if (ib == my_nb - 1)
                fa_step_lds<true>(Kl, Vl, ib * 32, q0, l15, quad, koff, voff,
                                  qf, o, m, l);
            else
                fa_step_lds<false>(Kl, Vl, ib * 32, q0, l15, quad, koff, voff,
                                   qf, o, m, l);
        }
        __syncthreads();
    }

    // epilogue: O rows are q=quad*4+r; fetch l from q=l15 lanes
    float inv[4];
#pragma unroll
    for (int r = 0; r < 4; ++r) inv[r] = 1.f / __shfl(l, quad * 20 + r);
#pragma unroll
    for (int n = 0; n < 8; ++n)
#pragma unroll
        for (int r = 0; r < 4; ++r) {
            int row = q0 + quad * 4 + r;
            O[(size_t)row * 4096 + h * 128 + n * 16 + l15] =
                f2bf(o[n][r] * inv[r]);
        }
}

__global__ __launch_bounds__(256) void flash_attn(
    const u16* __restrict__ Q, const u16* __restrict__ Kc,
    const u16* __restrict__ Vt, u16* __restrict__ O) {
    __shared__ __align__(16) short Kl[2 * 32 * 128];
    __shared__ __align__(16) short Vl[2 * 128 * 32];
    const int pp = blockIdx.x;   // 0..15  (q-tile pair: pp and 31-pp)
    const int h = blockIdx.y;    // 0..31
    const int kvh = h >> 2;
    const int t = threadIdx.x, wave = t >> 6;
    // wave w of tile pp pairs with wave 3-w of tile 31-pp: 68 lockstep
    // iterations per block, identical for every block (perfect balance)
    fa_task(Q, Kc, Vt, O, Kl, Vl, pp * 64 + wave * 16, 2 * pp + 2, h, kvh, t);
    const int tb = 31 - pp;
    fa_task(Q, Kc, Vt, O, Kl, Vl, tb * 64 + (3 - wave) * 16, 2 * tb + 2, h,
            kvh, t);
}

// ---------------------------------------------------------------------------
extern "C" void kernel_launch(void* const* d_in, const int* in_sizes, int n_in,
                              void* d_out, int out_size, void* d_ws,
                              size_t ws_size, hipStream_t stream) {
    const float* x  = (const float*)d_in[0];
    const float* wq = (const float*)d_in[1];
    const float* wk = (const float*)d_in[2];
    const float* wv = (const float*)d_in[3];
    const float* wo = (const float*)d_in[4];
    const float* fc = (const float*)d_in[5];
    const float* fs = (const float*)d_in[6];
    float* out = (float*)d_out;

    const int NX = 2048 * 4096;
    const int NQW = 4096 * 4096;
    const int NKW = 1024 * 4096;
    const int NKV = 2048 * 1024;

    u16* Q   = (u16*)d_ws;
    u16* Kc  = Q   + NX;
    u16* Vt  = Kc  + NKV;   // [1024 features][2048 seq]
    u16* Ao  = Vt  + NKV;
    u16* xb  = Ao  + NX;
    u16* wqb = xb  + NX;
    u16* wkb = wqb + NQW;
    u16* wvb = wkb + NKW;
    u16* wob = wvb + NKW;

    cvt_bf16<<<NX / (256 * 8), 256, 0, stream>>>(x, xb, NX);
    cvt_bf16<<<NQW / (256 * 8), 256, 0, stream>>>(wq, wqb, NQW);
    cvt_bf16<<<NKW / (256 * 8), 256, 0, stream>>>(wk, wkb, NKW);
    cvt_bf16<<<NKW / (256 * 8), 256, 0, stream>>>(wv, wvb, NKW);
    cvt_bf16<<<NQW / (256 * 8), 256, 0, stream>>>(wo, wob, NQW);

    qkv_proj8<<<dim3(8, 24), 512, 0, stream>>>(xb, wqb, wkb, wvb, Q, Kc, Vt);
    rope_kernel<<<(2048 * 32 * 64 + 255) / 256, 256, 0, stream>>>(Q, fc, fs, 32);
    rope_kernel<<<(2048 * 8 * 64 + 255) / 256, 256, 0, stream>>>(Kc, fc, fs, 8);
    flash_attn<<<dim3(16, 32), 256, 0, stream>>>(Q, Kc, Vt, Ao);
    oproj8<<<dim3(16, 16), 512, 0, stream>>>(Ao, wob, out);
}